// Round 3
// baseline (98.965 us; speedup 1.0000x reference)
//
#include <hip/hip_runtime.h>
#include <hip/hip_cooperative_groups.h>

namespace cg = cooperative_groups;

#define NN   50000
#define NE   800000
#define CH   64
#define NREL 8

#define NBLK 1024
#define NTHR 256

// Single cooperative kernel.
// Phase 1 (node-parallel, 16 threads/node): splice history row (~99.995% of
// nodes) or initialize out = x @ loop_w + bias for uncached nodes.
// grid.sync()
// Phase 2 (edge-parallel, wave-strided): ballot for edges whose destination
// is uncached (~40 of 800k); whole wave computes the 64-ch message
// (lane = channel) and atomically accumulates into out[dst].
__global__ __launch_bounds__(NTHR, 4)
void rgcn_fused(const float* __restrict__ x,
                const float* __restrict__ W,
                const float* __restrict__ loop_w,
                const float* __restrict__ bias,
                const float* __restrict__ hist,
                const int* __restrict__ src,
                const int* __restrict__ dst,
                const int* __restrict__ et,
                const int* __restrict__ hmap,
                float* __restrict__ out) {
    const int nthreads = NBLK * NTHR;
    const int gtid = blockIdx.x * blockDim.x + threadIdx.x;

    // ---- Phase 1: nodes ----
    float4* out4 = (float4*)out;
    for (int gid = gtid; gid < NN * 16; gid += nthreads) {
        int n = gid >> 4;
        int q = gid & 15;
        int hm = hmap[n];
        if (hm >= 0) {
            const float4* h4 = (const float4*)hist;
            out4[n * 16 + q] = h4[hm * 16 + q];
        } else {
            int c0 = q * 4;
            float4 acc = ((const float4*)bias)[q];
            const float* xr = x + n * CH;
#pragma unroll 8
            for (int i = 0; i < CH; ++i) {
                float xv = xr[i];
                float4 w = *(const float4*)(loop_w + i * CH + c0);
                acc.x += xv * w.x;
                acc.y += xv * w.y;
                acc.z += xv * w.z;
                acc.w += xv * w.w;
            }
            out4[n * 16 + q] = acc;
        }
    }

    cg::this_grid().sync();

    // ---- Phase 2: edges ----
    const int lane = threadIdx.x & 63;
    const int wave = gtid >> 6;
    const int nwaves = nthreads >> 6;
    for (int e0 = wave << 6; e0 < NE; e0 += nwaves << 6) {
        int e = e0 + lane;                 // NE % 64 == 0, no tail
        int d = dst[e];
        bool need = (hmap[d] < 0);
        unsigned long long mask = __ballot(need);
        while (mask) {
            int l = __ffsll((long long)mask) - 1;
            mask &= mask - 1;
            int ee = e0 + l;
            int dd = __shfl(d, l);
            int s  = src[ee];
            int r  = et[ee];
            const float* xr = x + s * CH;
            const float* wr = W + r * CH * CH + lane;
            float acc = 0.0f;
#pragma unroll 8
            for (int i = 0; i < CH; ++i)
                acc += xr[i] * wr[i * CH];
            atomicAdd(out + dd * CH + lane, acc);
        }
    }
}

extern "C" void kernel_launch(void* const* d_in, const int* in_sizes, int n_in,
                              void* d_out, int out_size, void* d_ws, size_t ws_size,
                              hipStream_t stream) {
    const float* x      = (const float*)d_in[0];
    const float* W      = (const float*)d_in[1];
    const float* loop_w = (const float*)d_in[2];
    const float* bias   = (const float*)d_in[3];
    const float* hist   = (const float*)d_in[4];
    const int*   src    = (const int*)d_in[5];
    const int*   dst    = (const int*)d_in[6];
    const int*   et     = (const int*)d_in[7];
    const int*   hmap   = (const int*)d_in[8];
    float* out = (float*)d_out;

    void* args[] = { (void*)&x, (void*)&W, (void*)&loop_w, (void*)&bias,
                     (void*)&hist, (void*)&src, (void*)&dst, (void*)&et,
                     (void*)&hmap, (void*)&out };
    hipLaunchCooperativeKernel((const void*)rgcn_fused,
                               dim3(NBLK), dim3(NTHR), args, 0, stream);
}

// Round 4
// 19.668 us; speedup vs baseline: 5.0318x; 5.0318x over previous
//
#include <hip/hip_runtime.h>

#define NN   50000
#define NE   800000
#define CH   64
#define NREL 8
#define NGRP (NE / 64)   // 12500 edge groups of 64

// Dispatch 1: 800k threads.
//  - Node phase (16 threads/node, float4): splice history row (~99.995% of
//    nodes) or out = x @ loop_w + bias for the ~2.5 uncached nodes.
//  - Edge phase (1 edge/thread): ballot "dst lacks history entry" per 64-edge
//    wave group; lane 0 stores the 64-bit mask to ws. Every slot is written
//    every call -> no ws initialization needed, fully deterministic.
__global__ __launch_bounds__(256)
void fused_main(const float* __restrict__ x,
                const float* __restrict__ loop_w,
                const float* __restrict__ bias,
                const float* __restrict__ hist,
                const int* __restrict__ dst,
                const int* __restrict__ hmap,
                float* __restrict__ out,
                unsigned long long* __restrict__ qmask) {
    int gtid = blockIdx.x * blockDim.x + threadIdx.x;   // exactly [0, 800000)

    // ---- node phase ----
    int n = gtid >> 4;
    int q = gtid & 15;
    int hm = hmap[n];
    float4* out4 = (float4*)out;
    if (hm >= 0) {
        out4[n * 16 + q] = ((const float4*)hist)[hm * 16 + q];
    } else {
        int c0 = q * 4;
        float4 acc = ((const float4*)bias)[q];
        const float* xr = x + n * CH;
#pragma unroll 8
        for (int i = 0; i < CH; ++i) {
            float xv = xr[i];
            float4 w = *(const float4*)(loop_w + i * CH + c0);
            acc.x += xv * w.x;
            acc.y += xv * w.y;
            acc.z += xv * w.z;
            acc.w += xv * w.w;
        }
        out4[n * 16 + q] = acc;
    }

    // ---- edge-scan phase ----
    int lane = threadIdx.x & 63;
    int grp = gtid >> 6;            // [0, 12500)
    int e = (grp << 6) + lane;
    int d = dst[e];
    unsigned long long m = __ballot(hmap[d] < 0);
    if (lane == 0) qmask[grp] = m;
}

// Dispatch 2: tiny. One thread per mask slot; each wave cooperatively
// recomputes and applies the (~40 grid-wide) qualifying edge messages.
// Base rows were written by dispatch 1 -> atomicAdd ordering is correct.
__global__ __launch_bounds__(256)
void apply_edges(const float* __restrict__ x,
                 const float* __restrict__ W,
                 const int* __restrict__ src,
                 const int* __restrict__ dst,
                 const int* __restrict__ et,
                 const unsigned long long* __restrict__ qmask,
                 float* __restrict__ out) {
    int gtid = blockIdx.x * blockDim.x + threadIdx.x;
    int lane = threadIdx.x & 63;
    unsigned long long m = (gtid < NGRP) ? qmask[gtid] : 0ULL;
    unsigned long long have = __ballot(m != 0ULL);
    int wave_base = gtid - lane;
    while (have) {
        int l = __ffsll((long long)have) - 1;
        have &= have - 1;
        int g = wave_base + l;
        unsigned long long wm = qmask[g];   // same addr all lanes -> broadcast
        while (wm) {
            int b = __ffsll((long long)wm) - 1;
            wm &= wm - 1;
            int e = (g << 6) + b;
            int s  = src[e];
            int r  = et[e];
            int dd = dst[e];
            const float* xr = x + s * CH;
            const float* wr = W + r * CH * CH + lane;
            float acc = 0.0f;
#pragma unroll 8
            for (int i = 0; i < CH; ++i)
                acc += xr[i] * wr[i * CH];
            atomicAdd(out + dd * CH + lane, acc);
        }
    }
}

// Fallback (ws too small, shouldn't happen): R2's two-kernel scheme.
__global__ void edge_fused_fb(const float* __restrict__ x,
                              const float* __restrict__ W,
                              const int* __restrict__ src,
                              const int* __restrict__ dst,
                              const int* __restrict__ et,
                              const int* __restrict__ hmap,
                              float* __restrict__ out) {
    int gtid = blockIdx.x * blockDim.x + threadIdx.x;
    int lane = threadIdx.x & 63;
    int e0 = (gtid >> 6) << 6;
    if (e0 >= NE) return;
    int e = e0 + lane;
    int d = dst[e];
    unsigned long long mask = __ballot(hmap[d] < 0);
    while (mask) {
        int l = __ffsll((long long)mask) - 1;
        mask &= mask - 1;
        int ee = e0 + l;
        int dd = __shfl(d, l);
        int s  = src[ee];
        int r  = et[ee];
        const float* xr = x + s * CH;
        const float* wr = W + r * CH * CH + lane;
        float acc = 0.0f;
#pragma unroll 8
        for (int i = 0; i < CH; ++i)
            acc += xr[i] * wr[i * CH];
        atomicAdd(out + dd * CH + lane, acc);
    }
}

extern "C" void kernel_launch(void* const* d_in, const int* in_sizes, int n_in,
                              void* d_out, int out_size, void* d_ws, size_t ws_size,
                              hipStream_t stream) {
    const float* x      = (const float*)d_in[0];
    const float* W      = (const float*)d_in[1];
    const float* loop_w = (const float*)d_in[2];
    const float* bias   = (const float*)d_in[3];
    const float* hist   = (const float*)d_in[4];
    const int*   src    = (const int*)d_in[5];
    const int*   dst    = (const int*)d_in[6];
    const int*   et     = (const int*)d_in[7];
    const int*   hmap   = (const int*)d_in[8];
    float* out = (float*)d_out;

    if (ws_size >= (size_t)NGRP * 8) {
        unsigned long long* qmask = (unsigned long long*)d_ws;
        fused_main<<<NN * 16 / 256, 256, 0, stream>>>(
            x, loop_w, bias, hist, dst, hmap, out, qmask);
        apply_edges<<<64, 256, 0, stream>>>(
            x, W, src, dst, et, qmask, out);
    } else {
        fused_main<<<NN * 16 / 256, 256, 0, stream>>>(
            x, loop_w, bias, hist, dst, hmap, out,
            (unsigned long long*)d_out /*unused dummy, won't be reached*/);
        edge_fused_fb<<<(NE + 255) / 256, 256, 0, stream>>>(
            x, W, src, dst, et, hmap, out);
    }
}

// Round 5
// 14.506 us; speedup vs baseline: 6.8222x; 1.3558x over previous
//
#include <hip/hip_runtime.h>

#define NN   50000
#define NE   800000
#define CH   64
#define NREL 8
#define NWRD ((NN + 63) / 64)   // 782 bitmap words

// Dispatch 1: 3125 blocks x 256.
//  Phase a (16 threads/node, float4): splice history row (~99.995% of nodes)
//  or out = x @ loop_w + bias for the ~2.5 uncached nodes.
//  Phase b (first 782 waves): ballot "hmap[node] < 0" over 64 nodes/wave,
//  lane 0 writes the 64-bit word -> 6.25 KB rare-node bitmap in d_ws.
//  Every word written every call -> deterministic, no init dispatch.
__global__ __launch_bounds__(256)
void splice_and_flag(const float* __restrict__ x,
                     const float* __restrict__ loop_w,
                     const float* __restrict__ bias,
                     const float* __restrict__ hist,
                     const int* __restrict__ hmap,
                     float* __restrict__ out,
                     unsigned long long* __restrict__ bitmap) {
    int gtid = blockIdx.x * blockDim.x + threadIdx.x;   // [0, 800000)

    // ---- phase a: node splice / self-loop ----
    int n = gtid >> 4;
    int q = gtid & 15;
    int hm = hmap[n];
    float4* out4 = (float4*)out;
    if (hm >= 0) {
        out4[n * 16 + q] = ((const float4*)hist)[hm * 16 + q];
    } else {
        int c0 = q * 4;
        float4 acc = ((const float4*)bias)[q];
        const float* xr = x + n * CH;
#pragma unroll 8
        for (int i = 0; i < CH; ++i) {
            float xv = xr[i];
            float4 w = *(const float4*)(loop_w + i * CH + c0);
            acc.x += xv * w.x;
            acc.y += xv * w.y;
            acc.z += xv * w.z;
            acc.w += xv * w.w;
        }
        out4[n * 16 + q] = acc;
    }

    // ---- phase b: rare-node bitmap ----
    int wid = gtid >> 6;
    if (wid < NWRD) {
        int lane = threadIdx.x & 63;
        int node = (wid << 6) + lane;
        int h = (node < NN) ? hmap[node] : 0;
        unsigned long long m = __ballot(h < 0);
        if (lane == 0) bitmap[wid] = m;
    }
}

// Dispatch 2: 3125 blocks x 256. Per edge: coalesced dst load + L1-resident
// bitmap probe (6.25 KB). Qualifying edges (~40 grid-wide): whole wave
// computes the 64-channel message (lane = channel), atomicAdd into out[dst].
__global__ __launch_bounds__(256)
void scan_apply(const float* __restrict__ x,
                const float* __restrict__ W,
                const int* __restrict__ src,
                const int* __restrict__ dst,
                const int* __restrict__ et,
                const unsigned long long* __restrict__ bitmap,
                float* __restrict__ out) {
    int gtid = blockIdx.x * blockDim.x + threadIdx.x;   // [0, 800000)
    int lane = threadIdx.x & 63;
    int e0 = gtid - lane;
    int d = dst[gtid];
    unsigned long long w = bitmap[d >> 6];
    bool need = (w >> (d & 63)) & 1ULL;
    unsigned long long mask = __ballot(need);
    while (mask) {
        int l = __ffsll((long long)mask) - 1;
        mask &= mask - 1;
        int e = e0 + l;
        int dd = __shfl(d, l);
        int s  = src[e];
        int r  = et[e];
        const float* xr = x + s * CH;
        const float* wr = W + r * CH * CH + lane;
        float acc = 0.0f;
#pragma unroll 8
        for (int i = 0; i < CH; ++i)
            acc += xr[i] * wr[i * CH];
        atomicAdd(out + dd * CH + lane, acc);
    }
}

// Fallback if ws is too small (won't trigger with the 268 MB ws): R2 scheme.
__global__ void edge_fused_fb(const float* __restrict__ x,
                              const float* __restrict__ W,
                              const int* __restrict__ src,
                              const int* __restrict__ dst,
                              const int* __restrict__ et,
                              const int* __restrict__ hmap,
                              float* __restrict__ out) {
    int gtid = blockIdx.x * blockDim.x + threadIdx.x;
    int lane = threadIdx.x & 63;
    int e0 = gtid - lane;
    if (e0 >= NE) return;
    int d = dst[e0 + lane];
    unsigned long long mask = __ballot(hmap[d] < 0);
    while (mask) {
        int l = __ffsll((long long)mask) - 1;
        mask &= mask - 1;
        int e = e0 + l;
        int dd = __shfl(d, l);
        int s  = src[e];
        int r  = et[e];
        const float* xr = x + s * CH;
        const float* wr = W + r * CH * CH + lane;
        float acc = 0.0f;
#pragma unroll 8
        for (int i = 0; i < CH; ++i)
            acc += xr[i] * wr[i * CH];
        atomicAdd(out + dd * CH + lane, acc);
    }
}

extern "C" void kernel_launch(void* const* d_in, const int* in_sizes, int n_in,
                              void* d_out, int out_size, void* d_ws, size_t ws_size,
                              hipStream_t stream) {
    const float* x      = (const float*)d_in[0];
    const float* W      = (const float*)d_in[1];
    const float* loop_w = (const float*)d_in[2];
    const float* bias   = (const float*)d_in[3];
    const float* hist   = (const float*)d_in[4];
    const int*   src    = (const int*)d_in[5];
    const int*   dst    = (const int*)d_in[6];
    const int*   et     = (const int*)d_in[7];
    const int*   hmap   = (const int*)d_in[8];
    float* out = (float*)d_out;

    if (ws_size >= (size_t)NWRD * 8) {
        unsigned long long* bitmap = (unsigned long long*)d_ws;
        splice_and_flag<<<NN * 16 / 256, 256, 0, stream>>>(
            x, loop_w, bias, hist, hmap, out, bitmap);
        scan_apply<<<NE / 256, 256, 0, stream>>>(
            x, W, src, dst, et, bitmap, out);
    } else {
        splice_and_flag<<<NN * 16 / 256, 256, 0, stream>>>(
            x, loop_w, bias, hist, hmap, out, (unsigned long long*)d_out);
        edge_fused_fb<<<(NE + 255) / 256, 256, 0, stream>>>(
            x, W, src, dst, et, hmap, out);
    }
}